// Round 2
// baseline (186.676 us; speedup 1.0000x reference)
//
#include <hip/hip_runtime.h>
#include <math.h>

// Output flat layout (harness reads whole d_out as float32):
//   [0 .. 3L)        input_tensor (L,3): X, Y, one_hot
//   [3L .. 3L+2B)    closest_points (B,2)
//   [3L+2B .. +B)    min_index written as float values
//
// Algorithm: spatial binning. Mesh is uniform in [0,10]^2; a 256x256 grid
// (cell w = 0.0390625, ~15 pts/cell) makes the argmin a ~3x3-cell ring
// search per receiver (expected NN dist ~0.005 << w). Exactness: d2 uses the
// identical fp32 sub/mul/mul/add sequence as numpy (no FMA contraction), and
// ties break to the lowest index, so atomic bin-order nondeterminism cannot
// change any output. Ring search stops only when best_d2 < 0.98*(r*w)^2 — a
// conservative bound on the min possible distance of any unsearched point.
//
// Falls back to the verified brute-force path if ws_size < ~4.6 MB
// (ws_size is fixed across calls, so the branch is graph-capture safe).

#define G      256
#define GG     (G * G)
#define CELLW  (10.0f / (float)G)     // 0.0390625, exact in fp32
#define INVW   ((float)G / 10.0f)     // 25.6
#define NCHUNK 1024

__device__ __forceinline__ int cell_of(float x, float y) {
    int cx = (int)(x * INVW);
    int cy = (int)(y * INVW);
    cx = min(max(cx, 0), G - 1);
    cy = min(max(cy, 0), G - 1);
    return cy * G + cx;
}

// ---------------- binning path ----------------

__global__ void zero_cnt_kernel(int* __restrict__ cnt) {
    int i = blockIdx.x * blockDim.x + threadIdx.x;
    if (i < GG) cnt[i] = 0;
}

// Fused: write (X, Y, 0) rows of input_tensor AND count points per cell.
__global__ void count_copy_kernel(const float2* __restrict__ mesh,
                                  float* __restrict__ out0,
                                  int* __restrict__ cnt, int L) {
    int i = blockIdx.x * blockDim.x + threadIdx.x;
    if (i < L) {
        float2 p = mesh[i];
        out0[3 * (size_t)i + 0] = p.x;
        out0[3 * (size_t)i + 1] = p.y;
        out0[3 * (size_t)i + 2] = 0.0f;
        atomicAdd(&cnt[cell_of(p.x, p.y)], 1);
    }
}

// Per-256-tile exclusive scan of cnt -> A; tile sums -> bs.
__global__ void scan_block_kernel(const int* __restrict__ cnt,
                                  int* __restrict__ A,
                                  int* __restrict__ bs) {
    __shared__ int sm[256];
    int t = threadIdx.x;
    int g = blockIdx.x * 256 + t;
    int v = cnt[g];
    sm[t] = v;
    __syncthreads();
    for (int o = 1; o < 256; o <<= 1) {
        int u = (t >= o) ? sm[t - o] : 0;
        __syncthreads();
        sm[t] += u;
        __syncthreads();
    }
    A[g] = sm[t] - v;                 // exclusive within tile
    if (t == 255) bs[blockIdx.x] = sm[255];
}

// Exclusive scan of the 256 tile sums, in place.
__global__ void scan_top_kernel(int* __restrict__ bs) {
    __shared__ int sm[256];
    int t = threadIdx.x;
    int v = bs[t];
    sm[t] = v;
    __syncthreads();
    for (int o = 1; o < 256; o <<= 1) {
        int u = (t >= o) ? sm[t - o] : 0;
        __syncthreads();
        sm[t] += u;
        __syncthreads();
    }
    bs[t] = sm[t] - v;
}

__global__ void add_off_kernel(int* __restrict__ A, const int* __restrict__ bs) {
    int i = blockIdx.x * blockDim.x + threadIdx.x;
    if (i < GG) A[i] += bs[i >> 8];
}

// Scatter point indices into contiguous per-cell bins. After this kernel,
// A[c] == end offset of cell c (start of cell c is A[c-1], or 0).
__global__ void place_kernel(const float2* __restrict__ mesh,
                             int* __restrict__ A,
                             int* __restrict__ pidx, int L) {
    int i = blockIdx.x * blockDim.x + threadIdx.x;
    if (i < L) {
        float2 p = mesh[i];
        int slot = atomicAdd(&A[cell_of(p.x, p.y)], 1);
        pidx[slot] = i;
    }
}

// One wave per receiver: expanding Chebyshev-ring search over the bins.
__global__ void search_final_kernel(const float2* __restrict__ mesh,
                                    const float* __restrict__ recv,
                                    const int* __restrict__ A,
                                    const int* __restrict__ pidx,
                                    float* __restrict__ out0,
                                    float* __restrict__ out1,
                                    float* __restrict__ out2, int B) {
    int wid = (blockIdx.x * blockDim.x + threadIdx.x) >> 6;
    int lane = threadIdx.x & 63;
    if (wid >= B) return;

    float rx = recv[3 * wid + 0];
    float ry = recv[3 * wid + 1];
    int cx = min(max((int)(rx * INVW), 0), G - 1);
    int cy = min(max((int)(ry * INVW), 0), G - 1);

    float bd2 = INFINITY;
    int bidx = 0x7fffffff;

    auto scan_cell = [&](int ux, int uy) {
        if (ux < 0 || ux >= G || uy < 0 || uy >= G) return;
        int c = uy * G + ux;
        int s = (c == 0) ? 0 : A[c - 1];
        int e = A[c];
        for (int j = s + lane; j < e; j += 64) {
            int pi = pidx[j];
            float2 p = mesh[pi];
            float dx = p.x - rx;
            float dy = p.y - ry;
            // identical fp32 sequence to numpy: sub, mul, mul, add (no FMA)
            float d2 = __fadd_rn(__fmul_rn(dx, dx), __fmul_rn(dy, dy));
            if (d2 < bd2 || (d2 == bd2 && pi < bidx)) { bd2 = d2; bidx = pi; }
        }
    };

    float rb;
    int ri;
    int r = 1;
    for (;;) {
        if (r == 1) {
            for (int uy = cy - 1; uy <= cy + 1; ++uy)
                for (int ux = cx - 1; ux <= cx + 1; ++ux)
                    scan_cell(ux, uy);
        } else {
            for (int ux = cx - r; ux <= cx + r; ++ux) {
                scan_cell(ux, cy - r);
                scan_cell(ux, cy + r);
            }
            for (int uy = cy - r + 1; uy <= cy + r - 1; ++uy) {
                scan_cell(cx - r, uy);
                scan_cell(cx + r, uy);
            }
        }
        // wave-wide lexicographic (d2, idx) min -> all lanes
        rb = bd2;
        ri = bidx;
        for (int m = 1; m < 64; m <<= 1) {
            float ob = __shfl_xor(rb, m, 64);
            int   oi = __shfl_xor(ri, m, 64);
            if (ob < rb || (ob == rb && oi < ri)) { rb = ob; ri = oi; }
        }
        bool covered = (cx - r <= 0 && cy - r <= 0 &&
                        cx + r >= G - 1 && cy + r >= G - 1);
        float bound = (float)r * CELLW;
        if (covered || rb < 0.98f * bound * bound) break;
        ++r;
    }

    if (lane == 0) {
        out2[wid] = (float)ri;                 // min_index as float
        float2 p = mesh[ri];
        out1[2 * wid + 0] = p.x;               // closest_points
        out1[2 * wid + 1] = p.y;
        out0[3 * (size_t)ri + 2] = 1.0f;       // one_hot scatter
        if (wid == 0 && B > 1) out0[2] = 1.0f; // reference's one_hot[0] = 1
    }
}

// ---------------- brute-force fallback (verified in R1) ----------------

__global__ void copy_xy_kernel(const float2* __restrict__ mesh,
                               float* __restrict__ out0, int L) {
    int i = blockIdx.x * blockDim.x + threadIdx.x;
    if (i < L) {
        float2 p = mesh[i];
        out0[3 * i + 0] = p.x;
        out0[3 * i + 1] = p.y;
        out0[3 * i + 2] = 0.0f;
    }
}

__global__ void partial_argmin_kernel(const float2* __restrict__ mesh,
                                      const float* __restrict__ recv,
                                      float* __restrict__ pd2,
                                      int* __restrict__ pidx,
                                      int L, int chunk) {
    const int b = threadIdx.x;
    const int c = blockIdx.x;
    const float rx = recv[3 * b + 0];
    const float ry = recv[3 * b + 1];
    int start = c * chunk;
    int end = min(start + chunk, L);

    float best = INFINITY;
    int bidx = 0x7fffffff;
    #pragma unroll 8
    for (int l = start; l < end; ++l) {
        float2 p = mesh[l];
        float dx = p.x - rx;
        float dy = p.y - ry;
        float d2 = __fadd_rn(__fmul_rn(dx, dx), __fmul_rn(dy, dy));
        if (d2 < best) { best = d2; bidx = l; }
    }
    pd2[c * blockDim.x + b] = best;
    pidx[c * blockDim.x + b] = bidx;
}

__global__ void reduce_finalize_kernel(const float2* __restrict__ mesh,
                                       const float* __restrict__ pd2,
                                       const int* __restrict__ pidx,
                                       float* __restrict__ out0,
                                       float* __restrict__ out1,
                                       float* __restrict__ out2,
                                       int B) {
    const int b = blockIdx.x;
    const int t = threadIdx.x;

    float best = INFINITY;
    int bidx = 0x7fffffff;
    for (int c = t; c < NCHUNK; c += blockDim.x) {
        float d2 = pd2[c * B + b];
        int   i  = pidx[c * B + b];
        if (d2 < best || (d2 == best && i < bidx)) { best = d2; bidx = i; }
    }

    __shared__ float sd[256];
    __shared__ int   si[256];
    sd[t] = best;
    si[t] = bidx;
    __syncthreads();
    for (int s = 128; s > 0; s >>= 1) {
        if (t < s) {
            float d2 = sd[t + s];
            int   i  = si[t + s];
            if (d2 < sd[t] || (d2 == sd[t] && i < si[t])) { sd[t] = d2; si[t] = i; }
        }
        __syncthreads();
    }

    if (t == 0) {
        int idx = si[0];
        out2[b] = (float)idx;
        float2 p = mesh[idx];
        out1[2 * b + 0] = p.x;
        out1[2 * b + 1] = p.y;
        out0[3 * (size_t)idx + 2] = 1.0f;
        if (b == 0) out0[2] = 1.0f;
    }
}

extern "C" void kernel_launch(void* const* d_in, const int* in_sizes, int n_in,
                              void* d_out, int out_size, void* d_ws, size_t ws_size,
                              hipStream_t stream) {
    const float* mesh = (const float*)d_in[0];   // (L,2) f32
    const float* recv = (const float*)d_in[1];   // (B,3) f32
    const int L = in_sizes[0] / 2;
    const int B = in_sizes[1] / 3;

    float* out0 = (float*)d_out;
    float* out1 = out0 + (size_t)3 * L;
    float* out2 = out1 + (size_t)2 * B;

    const size_t need = ((size_t)2 * GG + 1024 + (size_t)L) * sizeof(int);

    if (ws_size >= need) {
        int* cnt  = (int*)d_ws;           // GG
        int* A    = cnt + GG;             // GG
        int* bs   = A + GG;               // 256 (padded to 1024)
        int* pbuf = bs + 1024;            // L

        zero_cnt_kernel<<<GG / 256, 256, 0, stream>>>(cnt);
        count_copy_kernel<<<(L + 255) / 256, 256, 0, stream>>>(
            (const float2*)mesh, out0, cnt, L);
        scan_block_kernel<<<GG / 256, 256, 0, stream>>>(cnt, A, bs);
        scan_top_kernel<<<1, 256, 0, stream>>>(bs);
        add_off_kernel<<<GG / 256, 256, 0, stream>>>(A, bs);
        place_kernel<<<(L + 255) / 256, 256, 0, stream>>>(
            (const float2*)mesh, A, pbuf, L);
        search_final_kernel<<<(B * 64 + 255) / 256, 256, 0, stream>>>(
            (const float2*)mesh, recv, A, pbuf, out0, out1, out2, B);
    } else {
        float* pd2  = (float*)d_ws;
        int*   pidx = (int*)((char*)d_ws + sizeof(float) * (size_t)NCHUNK * B);
        const int chunk = (L + NCHUNK - 1) / NCHUNK;

        copy_xy_kernel<<<(L + 255) / 256, 256, 0, stream>>>(
            (const float2*)mesh, out0, L);
        partial_argmin_kernel<<<NCHUNK, B, 0, stream>>>(
            (const float2*)mesh, recv, pd2, pidx, L, chunk);
        reduce_finalize_kernel<<<B, 256, 0, stream>>>(
            (const float2*)mesh, pd2, pidx, out0, out1, out2, B);
    }
}

// Round 3
// 121.330 us; speedup vs baseline: 1.5386x; 1.5386x over previous
//
#include <hip/hip_runtime.h>
#include <math.h>

// Output flat layout (harness reads whole d_out as float32):
//   [0 .. 3L)        input_tensor (L,3): X, Y, one_hot
//   [3L .. 3L+2B)    closest_points (B,2)
//   [3L+2B .. +B)    min_index written as float values
//
// R3 algorithm: receiver-centric candidate filtering.
//   prep   (1 block):  zero counters; register each receiver into the <=9
//                      cells of its 3x3 neighborhood (cell->receiver lists).
//   filter (L/4 thr):  fused output copy (float4-vectorized) + candidate
//                      append: a point whose cell is in some receiver's 3x3
//                      stamp (~3.5% of points) is appended to that
//                      receiver's candidate buffer.
//   argmin (wave/rcv): exact lexicographic (d2, idx) min over candidates
//                      (identical fp32 sub/mul/mul/add as numpy, no FMA;
//                      ties -> lowest index, so atomic append order is
//                      irrelevant). Guarantee: any point within Euclid w of
//                      the receiver is within Chebyshev 1 of its cell, so
//                      best_d2 < 0.98*w^2 proves global optimality
//                      (true NN d2 ~3e-5 << w^2 = 1.5e-3). Otherwise (or on
//                      any overflow flag) the wave brute-forces its receiver
//                      over all L points in-kernel — never triggers in
//                      practice, preserves exactness always.

#define G      256
#define GG     (G * G)
#define CELLW  (10.0f / (float)G)     // 0.0390625
#define W2     (CELLW * CELLW)        // 0.00152587890625
#define INVW   ((float)G / 10.0f)     // 25.6
#define CAP_R  8                      // receivers per cell list
#define CAP_C  1024                   // candidates per receiver
#define NCHUNK 1024                   // brute-force fallback path

__device__ __forceinline__ int clampi(int v, int lo, int hi) {
    return min(max(v, lo), hi);
}

__device__ __forceinline__ int cell_of(float x, float y) {
    int cx = clampi((int)(x * INVW), 0, G - 1);
    int cy = clampi((int)(y * INVW), 0, G - 1);
    return cy * G + cx;
}

// ---------------- candidate path ----------------

// Single block: zero rl_cnt/cand_cnt/flag, then register receivers.
__global__ void prep_kernel(const float* __restrict__ recv,
                            int* __restrict__ rl_cnt,
                            int* __restrict__ rl,
                            int* __restrict__ cand_cnt,
                            int* __restrict__ flag, int B) {
    int t = threadIdx.x;
    for (int i = t; i < GG; i += 256) rl_cnt[i] = 0;
    for (int i = t; i < B; i += 256) { cand_cnt[i] = 0; flag[i] = 0; }
    __syncthreads();
    for (int r = t; r < B; r += 256) {
        float rx = recv[3 * r + 0];
        float ry = recv[3 * r + 1];
        int cx = clampi((int)(rx * INVW), 0, G - 1);
        int cy = clampi((int)(ry * INVW), 0, G - 1);
        for (int uy = cy - 1; uy <= cy + 1; ++uy) {
            if (uy < 0 || uy >= G) continue;
            for (int ux = cx - 1; ux <= cx + 1; ++ux) {
                if (ux < 0 || ux >= G) continue;
                int c = uy * G + ux;
                int s = atomicAdd(&rl_cnt[c], 1);
                if (s < CAP_R) rl[c * CAP_R + s] = r;
                else flag[r] = 1;   // r missing from this cell -> fallback r
            }
        }
    }
}

// 4 points per thread: float4 read of mesh, float4 writes of out0 rows,
// plus candidate append for points landing in a receiver-stamped cell.
__global__ void filter_copy_kernel(const float4* __restrict__ mesh4,
                                   float4* __restrict__ out4,
                                   const int* __restrict__ rl_cnt,
                                   const int* __restrict__ rl,
                                   int* __restrict__ cand_cnt,
                                   int* __restrict__ cand,
                                   int* __restrict__ flag, int L) {
    int t = blockIdx.x * blockDim.x + threadIdx.x;
    int p0 = t * 4;
    if (p0 >= L) return;

    float xs[4], ys[4];
    if (p0 + 3 < L) {
        float4 a = mesh4[2 * t];       // x0 y0 x1 y1
        float4 b = mesh4[2 * t + 1];   // x2 y2 x3 y3
        out4[3 * t + 0] = make_float4(a.x, a.y, 0.0f, a.z);
        out4[3 * t + 1] = make_float4(a.w, 0.0f, b.x, b.y);
        out4[3 * t + 2] = make_float4(0.0f, b.z, b.w, 0.0f);
        xs[0] = a.x; ys[0] = a.y; xs[1] = a.z; ys[1] = a.w;
        xs[2] = b.x; ys[2] = b.y; xs[3] = b.z; ys[3] = b.w;
    } else {
        const float2* mesh = (const float2*)mesh4;
        float* out0 = (float*)out4;
        for (int k = 0; k < 4; ++k) {
            int p = p0 + k;
            if (p >= L) { xs[k] = -1.0f; ys[k] = -1.0f; continue; }
            float2 pt = mesh[p];
            out0[3 * (size_t)p + 0] = pt.x;
            out0[3 * (size_t)p + 1] = pt.y;
            out0[3 * (size_t)p + 2] = 0.0f;
            xs[k] = pt.x; ys[k] = pt.y;
        }
    }

    #pragma unroll
    for (int k = 0; k < 4; ++k) {
        int p = p0 + k;
        if (p >= L) continue;
        int c = cell_of(xs[k], ys[k]);
        int n = min(rl_cnt[c], CAP_R);
        for (int s = 0; s < n; ++s) {
            int r = rl[c * CAP_R + s];
            int pos = atomicAdd(&cand_cnt[r], 1);
            if (pos < CAP_C) cand[r * CAP_C + pos] = p;
            else flag[r] = 1;          // candidate list overflow -> fallback
        }
    }
}

// One wave per receiver: exact lex-min over candidates; in-kernel
// brute-force fallback if the optimality bound or any flag fails.
__global__ void argmin_final_kernel(const float2* __restrict__ mesh,
                                    const float* __restrict__ recv,
                                    const int* __restrict__ cand_cnt,
                                    const int* __restrict__ cand,
                                    const int* __restrict__ flag,
                                    float* __restrict__ out0,
                                    float* __restrict__ out1,
                                    float* __restrict__ out2,
                                    int L, int B) {
    int wid = (blockIdx.x * blockDim.x + threadIdx.x) >> 6;
    int lane = threadIdx.x & 63;
    if (wid >= B) return;

    float rx = recv[3 * wid + 0];
    float ry = recv[3 * wid + 1];

    float bd2 = INFINITY;
    int bidx = 0x7fffffff;
    int n = min(cand_cnt[wid], CAP_C);
    for (int j = lane; j < n; j += 64) {
        int pi = cand[wid * CAP_C + j];
        float2 p = mesh[pi];
        float dx = p.x - rx;
        float dy = p.y - ry;
        float d2 = __fadd_rn(__fmul_rn(dx, dx), __fmul_rn(dy, dy));
        if (d2 < bd2 || (d2 == bd2 && pi < bidx)) { bd2 = d2; bidx = pi; }
    }
    float rb = bd2;
    int ri = bidx;
    for (int m = 1; m < 64; m <<= 1) {
        float ob = __shfl_xor(rb, m, 64);
        int   oi = __shfl_xor(ri, m, 64);
        if (ob < rb || (ob == rb && oi < ri)) { rb = ob; ri = oi; }
    }

    bool ok = (flag[wid] == 0) && (rb < 0.98f * W2);
    if (!ok) {
        // exact brute force for this receiver (correctness backstop)
        bd2 = INFINITY; bidx = 0x7fffffff;
        for (int j = lane; j < L; j += 64) {
            float2 p = mesh[j];
            float dx = p.x - rx;
            float dy = p.y - ry;
            float d2 = __fadd_rn(__fmul_rn(dx, dx), __fmul_rn(dy, dy));
            if (d2 < bd2 || (d2 == bd2 && j < bidx)) { bd2 = d2; bidx = j; }
        }
        rb = bd2; ri = bidx;
        for (int m = 1; m < 64; m <<= 1) {
            float ob = __shfl_xor(rb, m, 64);
            int   oi = __shfl_xor(ri, m, 64);
            if (ob < rb || (ob == rb && oi < ri)) { rb = ob; ri = oi; }
        }
    }

    if (lane == 0) {
        out2[wid] = (float)ri;                    // min_index as float
        float2 p = mesh[ri];
        out1[2 * wid + 0] = p.x;                  // closest_points
        out1[2 * wid + 1] = p.y;
        out0[3 * (size_t)ri + 2] = 1.0f;          // one_hot scatter
        if (wid == 0 && B > 1) out0[2] = 1.0f;    // reference's one_hot[0]=1
    }
}

// ---------------- brute-force fallback path (verified in R1) ----------------

__global__ void copy_xy_kernel(const float2* __restrict__ mesh,
                               float* __restrict__ out0, int L) {
    int i = blockIdx.x * blockDim.x + threadIdx.x;
    if (i < L) {
        float2 p = mesh[i];
        out0[3 * i + 0] = p.x;
        out0[3 * i + 1] = p.y;
        out0[3 * i + 2] = 0.0f;
    }
}

__global__ void partial_argmin_kernel(const float2* __restrict__ mesh,
                                      const float* __restrict__ recv,
                                      float* __restrict__ pd2,
                                      int* __restrict__ pidx,
                                      int L, int chunk) {
    const int b = threadIdx.x;
    const int c = blockIdx.x;
    const float rx = recv[3 * b + 0];
    const float ry = recv[3 * b + 1];
    int start = c * chunk;
    int end = min(start + chunk, L);

    float best = INFINITY;
    int bidx = 0x7fffffff;
    #pragma unroll 8
    for (int l = start; l < end; ++l) {
        float2 p = mesh[l];
        float dx = p.x - rx;
        float dy = p.y - ry;
        float d2 = __fadd_rn(__fmul_rn(dx, dx), __fmul_rn(dy, dy));
        if (d2 < best) { best = d2; bidx = l; }
    }
    pd2[c * blockDim.x + b] = best;
    pidx[c * blockDim.x + b] = bidx;
}

__global__ void reduce_finalize_kernel(const float2* __restrict__ mesh,
                                       const float* __restrict__ pd2,
                                       const int* __restrict__ pidx,
                                       float* __restrict__ out0,
                                       float* __restrict__ out1,
                                       float* __restrict__ out2,
                                       int B) {
    const int b = blockIdx.x;
    const int t = threadIdx.x;

    float best = INFINITY;
    int bidx = 0x7fffffff;
    for (int c = t; c < NCHUNK; c += blockDim.x) {
        float d2 = pd2[c * B + b];
        int   i  = pidx[c * B + b];
        if (d2 < best || (d2 == best && i < bidx)) { best = d2; bidx = i; }
    }

    __shared__ float sd[256];
    __shared__ int   si[256];
    sd[t] = best;
    si[t] = bidx;
    __syncthreads();
    for (int s = 128; s > 0; s >>= 1) {
        if (t < s) {
            float d2 = sd[t + s];
            int   i  = si[t + s];
            if (d2 < sd[t] || (d2 == sd[t] && i < si[t])) { sd[t] = d2; si[t] = i; }
        }
        __syncthreads();
    }

    if (t == 0) {
        int idx = si[0];
        out2[b] = (float)idx;
        float2 p = mesh[idx];
        out1[2 * b + 0] = p.x;
        out1[2 * b + 1] = p.y;
        out0[3 * (size_t)idx + 2] = 1.0f;
        if (b == 0) out0[2] = 1.0f;
    }
}

extern "C" void kernel_launch(void* const* d_in, const int* in_sizes, int n_in,
                              void* d_out, int out_size, void* d_ws, size_t ws_size,
                              hipStream_t stream) {
    const float* mesh = (const float*)d_in[0];   // (L,2) f32
    const float* recv = (const float*)d_in[1];   // (B,3) f32
    const int L = in_sizes[0] / 2;
    const int B = in_sizes[1] / 3;

    float* out0 = (float*)d_out;
    float* out1 = out0 + (size_t)3 * L;
    float* out2 = out1 + (size_t)2 * B;

    // workspace layout for the candidate path
    const size_t need = ((size_t)GG                 // rl_cnt
                         + (size_t)GG * CAP_R       // rl
                         + (size_t)B                // cand_cnt
                         + (size_t)B * CAP_C        // cand
                         + (size_t)B) * sizeof(int);// flag

    if (ws_size >= need) {
        int* rl_cnt   = (int*)d_ws;
        int* rl       = rl_cnt + GG;
        int* cand_cnt = rl + (size_t)GG * CAP_R;
        int* cand     = cand_cnt + B;
        int* flag     = cand + (size_t)B * CAP_C;

        prep_kernel<<<1, 256, 0, stream>>>(recv, rl_cnt, rl, cand_cnt, flag, B);
        filter_copy_kernel<<<(L / 4 + 255) / 256 + 1, 256, 0, stream>>>(
            (const float4*)mesh, (float4*)out0, rl_cnt, rl, cand_cnt, cand,
            flag, L);
        argmin_final_kernel<<<(B * 64 + 255) / 256, 256, 0, stream>>>(
            (const float2*)mesh, recv, cand_cnt, cand, flag,
            out0, out1, out2, L, B);
    } else {
        float* pd2  = (float*)d_ws;
        int*   pidx = (int*)((char*)d_ws + sizeof(float) * (size_t)NCHUNK * B);
        const int chunk = (L + NCHUNK - 1) / NCHUNK;

        copy_xy_kernel<<<(L + 255) / 256, 256, 0, stream>>>(
            (const float2*)mesh, out0, L);
        partial_argmin_kernel<<<NCHUNK, B, 0, stream>>>(
            (const float2*)mesh, recv, pd2, pidx, L, chunk);
        reduce_finalize_kernel<<<B, 256, 0, stream>>>(
            (const float2*)mesh, pd2, pidx, out0, out1, out2, B);
    }
}

// Round 4
// 120.879 us; speedup vs baseline: 1.5443x; 1.0037x over previous
//
#include <hip/hip_runtime.h>
#include <math.h>

// Output flat layout (harness reads whole d_out as float32):
//   [0 .. 3L)        input_tensor (L,3): X, Y, one_hot
//   [3L .. 3L+2B)    closest_points (B,2)
//   [3L+2B .. +B)    min_index written as float values
//
// R4: bitmap-gated candidate filter.
//   prep   (1 block):  zero the 8 KB stamped-cell bitmap + per-receiver
//                      counters; zero rl_cnt ONLY at stamped cells (<=2.3K),
//                      then register receivers (cell->receiver lists) and set
//                      bitmap bits. Two phases split by __syncthreads().
//   filter (L/4 thr):  fused float4 output copy + per-point 1-bit test in the
//                      8 KB bitmap (L1-resident). Only ~3.5% of points walk
//                      the receiver list and append (x, y, idx) to that
//                      receiver's candidate arrays.
//   argmin (wave/rcv): exact lexicographic (d2, idx) min over candidates —
//                      identical fp32 sub/mul/mul/add as numpy (no FMA),
//                      ties -> lowest index, so atomic append order is
//                      irrelevant. Optimality certificate: any point within
//                      Euclid CELLW of a receiver lies in its 3x3 stamp, so
//                      best_d2 < 0.98*CELLW^2 proves the global argmin
//                      (true NN d2 ~3e-5 << 1.5e-3). On any flag/bound
//                      failure the wave brute-forces all L points in-kernel.

#define G      256
#define GG     (G * G)
#define BMW    (GG / 32)              // bitmap words: 2048 (8 KB)
#define CELLW  (10.0f / (float)G)     // 0.0390625
#define W2     (CELLW * CELLW)        // 0.00152587890625
#define INVW   ((float)G / 10.0f)     // 25.6
#define CAP_R  8                      // receivers per cell list
#define CAP_C  512                    // candidates per receiver
#define NCHUNK 1024                   // brute-force fallback path

__device__ __forceinline__ int clampi(int v, int lo, int hi) {
    return min(max(v, lo), hi);
}

__device__ __forceinline__ int cell_of(float x, float y) {
    int cx = clampi((int)(x * INVW), 0, G - 1);
    int cy = clampi((int)(y * INVW), 0, G - 1);
    return cy * G + cx;
}

// ---------------- candidate path ----------------

// Single block. Phase 1: zero bitmap, per-receiver counters, and rl_cnt at
// stamped cells only. Phase 2: set bitmap bits + register receivers.
__global__ void prep_kernel(const float* __restrict__ recv,
                            unsigned* __restrict__ bm,
                            int* __restrict__ rl_cnt,
                            int* __restrict__ rl,
                            int* __restrict__ cand_cnt,
                            int* __restrict__ flag, int B) {
    int t = threadIdx.x;
    for (int i = t; i < BMW; i += 256) bm[i] = 0u;
    for (int i = t; i < B; i += 256) { cand_cnt[i] = 0; flag[i] = 0; }

    // stamped cells for this thread's receiver (B == 256 == blockDim)
    int cells[9];
    int nc = 0;
    if (t < B) {
        float rx = recv[3 * t + 0];
        float ry = recv[3 * t + 1];
        int cx = clampi((int)(rx * INVW), 0, G - 1);
        int cy = clampi((int)(ry * INVW), 0, G - 1);
        for (int uy = cy - 1; uy <= cy + 1; ++uy) {
            if (uy < 0 || uy >= G) continue;
            for (int ux = cx - 1; ux <= cx + 1; ++ux) {
                if (ux < 0 || ux >= G) continue;
                cells[nc++] = uy * G + ux;
            }
        }
        for (int k = 0; k < nc; ++k) rl_cnt[cells[k]] = 0;  // dup zeroes OK
    }
    __syncthreads();
    if (t < B) {
        for (int k = 0; k < nc; ++k) {
            int c = cells[k];
            atomicOr(&bm[c >> 5], 1u << (c & 31));
            int s = atomicAdd(&rl_cnt[c], 1);
            if (s < CAP_R) rl[c * CAP_R + s] = t;
            else flag[t] = 1;   // receiver t missing from cell c -> fallback t
        }
    }
}

// 4 points per thread: float4 mesh read, float4 out0 writes, 8 KB-bitmap
// gate (L1-resident) before the rare receiver-list walk + candidate append.
__global__ void filter_copy_kernel(const float4* __restrict__ mesh4,
                                   float4* __restrict__ out4,
                                   const unsigned* __restrict__ bm,
                                   const int* __restrict__ rl_cnt,
                                   const int* __restrict__ rl,
                                   int* __restrict__ cand_cnt,
                                   float* __restrict__ cand_x,
                                   float* __restrict__ cand_y,
                                   int* __restrict__ cand_i,
                                   int* __restrict__ flag, int L) {
    int t = blockIdx.x * blockDim.x + threadIdx.x;
    int p0 = t * 4;
    if (p0 >= L) return;

    float xs[4], ys[4];
    bool ok4 = (p0 + 3 < L);
    if (ok4) {
        float4 a = mesh4[2 * t];       // x0 y0 x1 y1
        float4 b = mesh4[2 * t + 1];   // x2 y2 x3 y3
        out4[3 * t + 0] = make_float4(a.x, a.y, 0.0f, a.z);
        out4[3 * t + 1] = make_float4(a.w, 0.0f, b.x, b.y);
        out4[3 * t + 2] = make_float4(0.0f, b.z, b.w, 0.0f);
        xs[0] = a.x; ys[0] = a.y; xs[1] = a.z; ys[1] = a.w;
        xs[2] = b.x; ys[2] = b.y; xs[3] = b.z; ys[3] = b.w;
    } else {
        const float2* mesh = (const float2*)mesh4;
        float* out0 = (float*)out4;
        for (int k = 0; k < 4; ++k) {
            int p = p0 + k;
            if (p >= L) { xs[k] = -100.0f; ys[k] = -100.0f; continue; }
            float2 pt = mesh[p];
            out0[3 * (size_t)p + 0] = pt.x;
            out0[3 * (size_t)p + 1] = pt.y;
            out0[3 * (size_t)p + 2] = 0.0f;
            xs[k] = pt.x; ys[k] = pt.y;
        }
    }

    // independent bitmap probes for all 4 points (ILP over the L1 hits)
    int c[4];
    unsigned w[4];
    #pragma unroll
    for (int k = 0; k < 4; ++k) c[k] = cell_of(xs[k], ys[k]);
    #pragma unroll
    for (int k = 0; k < 4; ++k) w[k] = bm[c[k] >> 5];

    #pragma unroll
    for (int k = 0; k < 4; ++k) {
        int p = p0 + k;
        if (p >= L) continue;
        if ((w[k] >> (c[k] & 31)) & 1u) {
            int n = min(rl_cnt[c[k]], CAP_R);
            for (int s = 0; s < n; ++s) {
                int r = rl[c[k] * CAP_R + s];
                int pos = atomicAdd(&cand_cnt[r], 1);
                if (pos < CAP_C) {
                    size_t o = (size_t)r * CAP_C + pos;
                    cand_x[o] = xs[k];
                    cand_y[o] = ys[k];
                    cand_i[o] = p;
                } else {
                    flag[r] = 1;   // candidate overflow -> fallback receiver r
                }
            }
        }
    }
}

// One wave per receiver: exact lex-min over its candidate arrays (coalesced
// reads, no gather); in-kernel brute-force fallback on flag/bound failure.
__global__ void argmin_final_kernel(const float2* __restrict__ mesh,
                                    const float* __restrict__ recv,
                                    const int* __restrict__ cand_cnt,
                                    const float* __restrict__ cand_x,
                                    const float* __restrict__ cand_y,
                                    const int* __restrict__ cand_i,
                                    const int* __restrict__ flag,
                                    float* __restrict__ out0,
                                    float* __restrict__ out1,
                                    float* __restrict__ out2,
                                    int L, int B) {
    int wid = (blockIdx.x * blockDim.x + threadIdx.x) >> 6;
    int lane = threadIdx.x & 63;
    if (wid >= B) return;

    float rx = recv[3 * wid + 0];
    float ry = recv[3 * wid + 1];

    float bd2 = INFINITY;
    int bidx = 0x7fffffff;
    int n = min(cand_cnt[wid], CAP_C);
    size_t base = (size_t)wid * CAP_C;
    for (int j = lane; j < n; j += 64) {
        float px = cand_x[base + j];
        float py = cand_y[base + j];
        int pi = cand_i[base + j];
        float dx = px - rx;
        float dy = py - ry;
        float d2 = __fadd_rn(__fmul_rn(dx, dx), __fmul_rn(dy, dy));
        if (d2 < bd2 || (d2 == bd2 && pi < bidx)) { bd2 = d2; bidx = pi; }
    }
    float rb = bd2;
    int ri = bidx;
    for (int m = 1; m < 64; m <<= 1) {
        float ob = __shfl_xor(rb, m, 64);
        int   oi = __shfl_xor(ri, m, 64);
        if (ob < rb || (ob == rb && oi < ri)) { rb = ob; ri = oi; }
    }

    bool ok = (flag[wid] == 0) && (rb < 0.98f * W2);
    if (!ok) {
        bd2 = INFINITY; bidx = 0x7fffffff;
        for (int j = lane; j < L; j += 64) {
            float2 p = mesh[j];
            float dx = p.x - rx;
            float dy = p.y - ry;
            float d2 = __fadd_rn(__fmul_rn(dx, dx), __fmul_rn(dy, dy));
            if (d2 < bd2 || (d2 == bd2 && j < bidx)) { bd2 = d2; bidx = j; }
        }
        rb = bd2; ri = bidx;
        for (int m = 1; m < 64; m <<= 1) {
            float ob = __shfl_xor(rb, m, 64);
            int   oi = __shfl_xor(ri, m, 64);
            if (ob < rb || (ob == rb && oi < ri)) { rb = ob; ri = oi; }
        }
    }

    if (lane == 0) {
        out2[wid] = (float)ri;                    // min_index as float
        float2 p = mesh[ri];
        out1[2 * wid + 0] = p.x;                  // closest_points
        out1[2 * wid + 1] = p.y;
        out0[3 * (size_t)ri + 2] = 1.0f;          // one_hot scatter
        if (wid == 0 && B > 1) out0[2] = 1.0f;    // reference's one_hot[0]=1
    }
}

// ---------------- brute-force fallback path (verified in R1) ----------------

__global__ void copy_xy_kernel(const float2* __restrict__ mesh,
                               float* __restrict__ out0, int L) {
    int i = blockIdx.x * blockDim.x + threadIdx.x;
    if (i < L) {
        float2 p = mesh[i];
        out0[3 * i + 0] = p.x;
        out0[3 * i + 1] = p.y;
        out0[3 * i + 2] = 0.0f;
    }
}

__global__ void partial_argmin_kernel(const float2* __restrict__ mesh,
                                      const float* __restrict__ recv,
                                      float* __restrict__ pd2,
                                      int* __restrict__ pidx,
                                      int L, int chunk) {
    const int b = threadIdx.x;
    const int c = blockIdx.x;
    const float rx = recv[3 * b + 0];
    const float ry = recv[3 * b + 1];
    int start = c * chunk;
    int end = min(start + chunk, L);

    float best = INFINITY;
    int bidx = 0x7fffffff;
    #pragma unroll 8
    for (int l = start; l < end; ++l) {
        float2 p = mesh[l];
        float dx = p.x - rx;
        float dy = p.y - ry;
        float d2 = __fadd_rn(__fmul_rn(dx, dx), __fmul_rn(dy, dy));
        if (d2 < best) { best = d2; bidx = l; }
    }
    pd2[c * blockDim.x + b] = best;
    pidx[c * blockDim.x + b] = bidx;
}

__global__ void reduce_finalize_kernel(const float2* __restrict__ mesh,
                                       const float* __restrict__ pd2,
                                       const int* __restrict__ pidx,
                                       float* __restrict__ out0,
                                       float* __restrict__ out1,
                                       float* __restrict__ out2,
                                       int B) {
    const int b = blockIdx.x;
    const int t = threadIdx.x;

    float best = INFINITY;
    int bidx = 0x7fffffff;
    for (int c = t; c < NCHUNK; c += blockDim.x) {
        float d2 = pd2[c * B + b];
        int   i  = pidx[c * B + b];
        if (d2 < best || (d2 == best && i < bidx)) { best = d2; bidx = i; }
    }

    __shared__ float sd[256];
    __shared__ int   si[256];
    sd[t] = best;
    si[t] = bidx;
    __syncthreads();
    for (int s = 128; s > 0; s >>= 1) {
        if (t < s) {
            float d2 = sd[t + s];
            int   i  = si[t + s];
            if (d2 < sd[t] || (d2 == sd[t] && i < si[t])) { sd[t] = d2; si[t] = i; }
        }
        __syncthreads();
    }

    if (t == 0) {
        int idx = si[0];
        out2[b] = (float)idx;
        float2 p = mesh[idx];
        out1[2 * b + 0] = p.x;
        out1[2 * b + 1] = p.y;
        out0[3 * (size_t)idx + 2] = 1.0f;
        if (b == 0) out0[2] = 1.0f;
    }
}

extern "C" void kernel_launch(void* const* d_in, const int* in_sizes, int n_in,
                              void* d_out, int out_size, void* d_ws, size_t ws_size,
                              hipStream_t stream) {
    const float* mesh = (const float*)d_in[0];   // (L,2) f32
    const float* recv = (const float*)d_in[1];   // (B,3) f32
    const int L = in_sizes[0] / 2;
    const int B = in_sizes[1] / 3;

    float* out0 = (float*)d_out;
    float* out1 = out0 + (size_t)3 * L;
    float* out2 = out1 + (size_t)2 * B;

    // workspace layout for the candidate path (~3.9 MB for B=256)
    const size_t need = ((size_t)BMW                // bm
                         + (size_t)GG               // rl_cnt
                         + (size_t)GG * CAP_R       // rl
                         + (size_t)B                // cand_cnt
                         + (size_t)B                // flag
                         + (size_t)3 * B * CAP_C    // cand_x/y/i
                        ) * sizeof(int);

    if (ws_size >= need && B <= 256) {
        unsigned* bm     = (unsigned*)d_ws;
        int* rl_cnt      = (int*)(bm + BMW);
        int* rl          = rl_cnt + GG;
        int* cand_cnt    = rl + (size_t)GG * CAP_R;
        int* flag        = cand_cnt + B;
        float* cand_x    = (float*)(flag + B);
        float* cand_y    = cand_x + (size_t)B * CAP_C;
        int* cand_i      = (int*)(cand_y + (size_t)B * CAP_C);

        prep_kernel<<<1, 256, 0, stream>>>(recv, bm, rl_cnt, rl,
                                           cand_cnt, flag, B);
        filter_copy_kernel<<<(L + 1023) / 1024, 256, 0, stream>>>(
            (const float4*)mesh, (float4*)out0, bm, rl_cnt, rl,
            cand_cnt, cand_x, cand_y, cand_i, flag, L);
        argmin_final_kernel<<<(B * 64 + 255) / 256, 256, 0, stream>>>(
            (const float2*)mesh, recv, cand_cnt, cand_x, cand_y, cand_i,
            flag, out0, out1, out2, L, B);
    } else {
        float* pd2  = (float*)d_ws;
        int*   pidx = (int*)((char*)d_ws + sizeof(float) * (size_t)NCHUNK * B);
        const int chunk = (L + NCHUNK - 1) / NCHUNK;

        copy_xy_kernel<<<(L + 255) / 256, 256, 0, stream>>>(
            (const float2*)mesh, out0, L);
        partial_argmin_kernel<<<NCHUNK, B, 0, stream>>>(
            (const float2*)mesh, recv, pd2, pidx, L, chunk);
        reduce_finalize_kernel<<<B, 256, 0, stream>>>(
            (const float2*)mesh, pd2, pidx, out0, out1, out2, B);
    }
}

// Round 5
// 88.954 us; speedup vs baseline: 2.0986x; 1.3589x over previous
//
#include <hip/hip_runtime.h>
#include <math.h>

// Output flat layout (harness reads whole d_out as float32):
//   [0 .. 3L)        input_tensor (L,3): X, Y, one_hot
//   [3L .. 3L+2B)    closest_points (B,2)
//   [3L+2B .. +B)    min_index written as float values
//
// R5: R4 + cache-line-padded atomic counters.
//   R4 post-mortem: filter_copy stuck at ~48 us with VALUBusy 1.7% and HBM 5%
//   regardless of the bitmap gate -> the serializer is the ~35K candidate
//   appends whose atomicAdd targets (cand_cnt[256]) shared 4 cache lines.
//   Fix: stride counters by 16 ints (64 B) so each receiver's counter owns a
//   line; contended-line serialization at the L2 slice disappears.
//
// Exactness (unchanged): d2 = fp32 sub/mul/mul/add exactly as numpy (no FMA
// contraction); argmin is lexicographic (d2, idx) so atomic append order is
// irrelevant. Optimality certificate: any point within Euclid CELLW of a
// receiver lies in its 3x3 cell stamp, so best_d2 < 0.98*CELLW^2 proves the
// global argmin (true NN d2 ~3e-5 << CELLW^2 = 1.5e-3). On any flag or bound
// failure the wave brute-forces all L points in-kernel (exact backstop).

#define G      256
#define GG     (G * G)
#define BMW    (GG / 32)              // bitmap words: 2048 (8 KB)
#define CELLW  (10.0f / (float)G)     // 0.0390625
#define W2     (CELLW * CELLW)        // 0.00152587890625
#define INVW   ((float)G / 10.0f)     // 25.6
#define CAP_R  8                      // receivers per cell list
#define CAP_C  512                    // candidates per receiver
#define CNTS   16                     // counter stride in ints (64 B line)
#define NCHUNK 1024                   // brute-force fallback path

__device__ __forceinline__ int clampi(int v, int lo, int hi) {
    return min(max(v, lo), hi);
}

__device__ __forceinline__ int cell_of(float x, float y) {
    int cx = clampi((int)(x * INVW), 0, G - 1);
    int cy = clampi((int)(y * INVW), 0, G - 1);
    return cy * G + cx;
}

// ---------------- candidate path ----------------

// Single block. Phase 1: zero bitmap, padded per-receiver counters/flags,
// and rl_cnt at stamped cells only. Phase 2: set bits + register receivers.
__global__ void prep_kernel(const float* __restrict__ recv,
                            unsigned* __restrict__ bm,
                            int* __restrict__ rl_cnt,
                            int* __restrict__ rl,
                            int* __restrict__ cand_cnt,
                            int* __restrict__ flag, int B) {
    int t = threadIdx.x;
    for (int i = t; i < BMW; i += 256) bm[i] = 0u;
    for (int i = t; i < B; i += 256) { cand_cnt[i * CNTS] = 0; flag[i * CNTS] = 0; }

    int cells[9];
    int nc = 0;
    if (t < B) {
        float rx = recv[3 * t + 0];
        float ry = recv[3 * t + 1];
        int cx = clampi((int)(rx * INVW), 0, G - 1);
        int cy = clampi((int)(ry * INVW), 0, G - 1);
        for (int uy = cy - 1; uy <= cy + 1; ++uy) {
            if (uy < 0 || uy >= G) continue;
            for (int ux = cx - 1; ux <= cx + 1; ++ux) {
                if (ux < 0 || ux >= G) continue;
                cells[nc++] = uy * G + ux;
            }
        }
        for (int k = 0; k < nc; ++k) rl_cnt[cells[k]] = 0;  // dup zeroes OK
    }
    __syncthreads();
    if (t < B) {
        for (int k = 0; k < nc; ++k) {
            int c = cells[k];
            atomicOr(&bm[c >> 5], 1u << (c & 31));
            int s = atomicAdd(&rl_cnt[c], 1);
            if (s < CAP_R) rl[c * CAP_R + s] = t;
            else flag[t * CNTS] = 1;   // receiver t missing from cell c
        }
    }
}

// 4 points per thread: float4 mesh read, float4 out0 writes, 8 KB bitmap
// gate before the rare receiver-list walk + candidate append.
__global__ void filter_copy_kernel(const float4* __restrict__ mesh4,
                                   float4* __restrict__ out4,
                                   const unsigned* __restrict__ bm,
                                   const int* __restrict__ rl_cnt,
                                   const int* __restrict__ rl,
                                   int* __restrict__ cand_cnt,
                                   float* __restrict__ cand_x,
                                   float* __restrict__ cand_y,
                                   int* __restrict__ cand_i,
                                   int* __restrict__ flag, int L) {
    int t = blockIdx.x * blockDim.x + threadIdx.x;
    int p0 = t * 4;
    if (p0 >= L) return;

    float xs[4], ys[4];
    if (p0 + 3 < L) {
        float4 a = mesh4[2 * t];       // x0 y0 x1 y1
        float4 b = mesh4[2 * t + 1];   // x2 y2 x3 y3
        out4[3 * t + 0] = make_float4(a.x, a.y, 0.0f, a.z);
        out4[3 * t + 1] = make_float4(a.w, 0.0f, b.x, b.y);
        out4[3 * t + 2] = make_float4(0.0f, b.z, b.w, 0.0f);
        xs[0] = a.x; ys[0] = a.y; xs[1] = a.z; ys[1] = a.w;
        xs[2] = b.x; ys[2] = b.y; xs[3] = b.z; ys[3] = b.w;
    } else {
        const float2* mesh = (const float2*)mesh4;
        float* out0 = (float*)out4;
        for (int k = 0; k < 4; ++k) {
            int p = p0 + k;
            if (p >= L) { xs[k] = -100.0f; ys[k] = -100.0f; continue; }
            float2 pt = mesh[p];
            out0[3 * (size_t)p + 0] = pt.x;
            out0[3 * (size_t)p + 1] = pt.y;
            out0[3 * (size_t)p + 2] = 0.0f;
            xs[k] = pt.x; ys[k] = pt.y;
        }
    }

    int c[4];
    unsigned w[4];
    #pragma unroll
    for (int k = 0; k < 4; ++k) c[k] = cell_of(xs[k], ys[k]);
    #pragma unroll
    for (int k = 0; k < 4; ++k) w[k] = bm[c[k] >> 5];

    #pragma unroll
    for (int k = 0; k < 4; ++k) {
        int p = p0 + k;
        if (p >= L) continue;
        if ((w[k] >> (c[k] & 31)) & 1u) {
            int n = min(rl_cnt[c[k]], CAP_R);
            for (int s = 0; s < n; ++s) {
                int r = rl[c[k] * CAP_R + s];
                int pos = atomicAdd(&cand_cnt[r * CNTS], 1);  // line-private
                if (pos < CAP_C) {
                    size_t o = (size_t)r * CAP_C + pos;
                    cand_x[o] = xs[k];
                    cand_y[o] = ys[k];
                    cand_i[o] = p;
                } else {
                    flag[r * CNTS] = 1;   // overflow -> fallback receiver r
                }
            }
        }
    }
}

// One wave per receiver: exact lex-min over its candidate arrays; in-kernel
// brute-force fallback on flag/bound failure.
__global__ void argmin_final_kernel(const float2* __restrict__ mesh,
                                    const float* __restrict__ recv,
                                    const int* __restrict__ cand_cnt,
                                    const float* __restrict__ cand_x,
                                    const float* __restrict__ cand_y,
                                    const int* __restrict__ cand_i,
                                    const int* __restrict__ flag,
                                    float* __restrict__ out0,
                                    float* __restrict__ out1,
                                    float* __restrict__ out2,
                                    int L, int B) {
    int wid = (blockIdx.x * blockDim.x + threadIdx.x) >> 6;
    int lane = threadIdx.x & 63;
    if (wid >= B) return;

    float rx = recv[3 * wid + 0];
    float ry = recv[3 * wid + 1];

    float bd2 = INFINITY;
    int bidx = 0x7fffffff;
    int n = min(cand_cnt[wid * CNTS], CAP_C);
    size_t base = (size_t)wid * CAP_C;
    for (int j = lane; j < n; j += 64) {
        float px = cand_x[base + j];
        float py = cand_y[base + j];
        int pi = cand_i[base + j];
        float dx = px - rx;
        float dy = py - ry;
        float d2 = __fadd_rn(__fmul_rn(dx, dx), __fmul_rn(dy, dy));
        if (d2 < bd2 || (d2 == bd2 && pi < bidx)) { bd2 = d2; bidx = pi; }
    }
    float rb = bd2;
    int ri = bidx;
    for (int m = 1; m < 64; m <<= 1) {
        float ob = __shfl_xor(rb, m, 64);
        int   oi = __shfl_xor(ri, m, 64);
        if (ob < rb || (ob == rb && oi < ri)) { rb = ob; ri = oi; }
    }

    bool ok = (flag[wid * CNTS] == 0) && (rb < 0.98f * W2);
    if (!ok) {
        bd2 = INFINITY; bidx = 0x7fffffff;
        for (int j = lane; j < L; j += 64) {
            float2 p = mesh[j];
            float dx = p.x - rx;
            float dy = p.y - ry;
            float d2 = __fadd_rn(__fmul_rn(dx, dx), __fmul_rn(dy, dy));
            if (d2 < bd2 || (d2 == bd2 && j < bidx)) { bd2 = d2; bidx = j; }
        }
        rb = bd2; ri = bidx;
        for (int m = 1; m < 64; m <<= 1) {
            float ob = __shfl_xor(rb, m, 64);
            int   oi = __shfl_xor(ri, m, 64);
            if (ob < rb || (ob == rb && oi < ri)) { rb = ob; ri = oi; }
        }
    }

    if (lane == 0) {
        out2[wid] = (float)ri;                    // min_index as float
        float2 p = mesh[ri];
        out1[2 * wid + 0] = p.x;                  // closest_points
        out1[2 * wid + 1] = p.y;
        out0[3 * (size_t)ri + 2] = 1.0f;          // one_hot scatter
        if (wid == 0 && B > 1) out0[2] = 1.0f;    // reference's one_hot[0]=1
    }
}

// ---------------- brute-force fallback path (verified in R1) ----------------

__global__ void copy_xy_kernel(const float2* __restrict__ mesh,
                               float* __restrict__ out0, int L) {
    int i = blockIdx.x * blockDim.x + threadIdx.x;
    if (i < L) {
        float2 p = mesh[i];
        out0[3 * i + 0] = p.x;
        out0[3 * i + 1] = p.y;
        out0[3 * i + 2] = 0.0f;
    }
}

__global__ void partial_argmin_kernel(const float2* __restrict__ mesh,
                                      const float* __restrict__ recv,
                                      float* __restrict__ pd2,
                                      int* __restrict__ pidx,
                                      int L, int chunk) {
    const int b = threadIdx.x;
    const int c = blockIdx.x;
    const float rx = recv[3 * b + 0];
    const float ry = recv[3 * b + 1];
    int start = c * chunk;
    int end = min(start + chunk, L);

    float best = INFINITY;
    int bidx = 0x7fffffff;
    #pragma unroll 8
    for (int l = start; l < end; ++l) {
        float2 p = mesh[l];
        float dx = p.x - rx;
        float dy = p.y - ry;
        float d2 = __fadd_rn(__fmul_rn(dx, dx), __fmul_rn(dy, dy));
        if (d2 < best) { best = d2; bidx = l; }
    }
    pd2[c * blockDim.x + b] = best;
    pidx[c * blockDim.x + b] = bidx;
}

__global__ void reduce_finalize_kernel(const float2* __restrict__ mesh,
                                       const float* __restrict__ pd2,
                                       const int* __restrict__ pidx,
                                       float* __restrict__ out0,
                                       float* __restrict__ out1,
                                       float* __restrict__ out2,
                                       int B) {
    const int b = blockIdx.x;
    const int t = threadIdx.x;

    float best = INFINITY;
    int bidx = 0x7fffffff;
    for (int c = t; c < NCHUNK; c += blockDim.x) {
        float d2 = pd2[c * B + b];
        int   i  = pidx[c * B + b];
        if (d2 < best || (d2 == best && i < bidx)) { best = d2; bidx = i; }
    }

    __shared__ float sd[256];
    __shared__ int   si[256];
    sd[t] = best;
    si[t] = bidx;
    __syncthreads();
    for (int s = 128; s > 0; s >>= 1) {
        if (t < s) {
            float d2 = sd[t + s];
            int   i  = si[t + s];
            if (d2 < sd[t] || (d2 == sd[t] && i < si[t])) { sd[t] = d2; si[t] = i; }
        }
        __syncthreads();
    }

    if (t == 0) {
        int idx = si[0];
        out2[b] = (float)idx;
        float2 p = mesh[idx];
        out1[2 * b + 0] = p.x;
        out1[2 * b + 1] = p.y;
        out0[3 * (size_t)idx + 2] = 1.0f;
        if (b == 0) out0[2] = 1.0f;
    }
}

extern "C" void kernel_launch(void* const* d_in, const int* in_sizes, int n_in,
                              void* d_out, int out_size, void* d_ws, size_t ws_size,
                              hipStream_t stream) {
    const float* mesh = (const float*)d_in[0];   // (L,2) f32
    const float* recv = (const float*)d_in[1];   // (B,3) f32
    const int L = in_sizes[0] / 2;
    const int B = in_sizes[1] / 3;

    float* out0 = (float*)d_out;
    float* out1 = out0 + (size_t)3 * L;
    float* out2 = out1 + (size_t)2 * B;

    // workspace layout for the candidate path (~4.0 MB for B=256)
    const size_t need = ((size_t)BMW                // bm
                         + (size_t)GG               // rl_cnt
                         + (size_t)GG * CAP_R       // rl
                         + (size_t)B * CNTS         // cand_cnt (line-padded)
                         + (size_t)B * CNTS         // flag (line-padded)
                         + (size_t)3 * B * CAP_C    // cand_x/y/i
                        ) * sizeof(int);

    if (ws_size >= need && B <= 256) {
        unsigned* bm     = (unsigned*)d_ws;
        int* rl_cnt      = (int*)(bm + BMW);
        int* rl          = rl_cnt + GG;
        int* cand_cnt    = rl + (size_t)GG * CAP_R;
        int* flag        = cand_cnt + (size_t)B * CNTS;
        float* cand_x    = (float*)(flag + (size_t)B * CNTS);
        float* cand_y    = cand_x + (size_t)B * CAP_C;
        int* cand_i      = (int*)(cand_y + (size_t)B * CAP_C);

        prep_kernel<<<1, 256, 0, stream>>>(recv, bm, rl_cnt, rl,
                                           cand_cnt, flag, B);
        filter_copy_kernel<<<(L + 1023) / 1024, 256, 0, stream>>>(
            (const float4*)mesh, (float4*)out0, bm, rl_cnt, rl,
            cand_cnt, cand_x, cand_y, cand_i, flag, L);
        argmin_final_kernel<<<(B * 64 + 255) / 256, 256, 0, stream>>>(
            (const float2*)mesh, recv, cand_cnt, cand_x, cand_y, cand_i,
            flag, out0, out1, out2, L, B);
    } else {
        float* pd2  = (float*)d_ws;
        int*   pidx = (int*)((char*)d_ws + sizeof(float) * (size_t)NCHUNK * B);
        const int chunk = (L + NCHUNK - 1) / NCHUNK;

        copy_xy_kernel<<<(L + 255) / 256, 256, 0, stream>>>(
            (const float2*)mesh, out0, L);
        partial_argmin_kernel<<<NCHUNK, B, 0, stream>>>(
            (const float2*)mesh, recv, pd2, pidx, L, chunk);
        reduce_finalize_kernel<<<B, 256, 0, stream>>>(
            (const float2*)mesh, pd2, pidx, out0, out1, out2, B);
    }
}